// Round 6
// baseline (229.140 us; speedup 1.0000x reference)
//
#include <hip/hip_runtime.h>

#define BB 2
#define TT 2048
#define DD 1024
#define HH 16
#define DHD 64
#define MM (BB*TT)   // 4096

typedef __attribute__((ext_vector_type(8))) short short8;
typedef __attribute__((ext_vector_type(4))) float float4v;
typedef __attribute__((ext_vector_type(16))) float f32x16;
typedef unsigned short u16;

__device__ inline float bf2f(u16 u) {
    union { unsigned int i; float f; } v;
    v.i = ((unsigned int)u) << 16;
    return v.f;
}
__device__ inline u16 f2bf(float f) {
    union { float f; unsigned int i; } v;
    v.f = f;
    unsigned int x = v.i;
    unsigned int r = (x + 0x7fffu + ((x >> 16) & 1u)) >> 16;
    return (u16)r;
}
// truncating bf16 pair-pack (bit-identical to the old P-store path)
__device__ inline unsigned packtr(float x, float y) {
    union { float f; unsigned u; } a, b;
    a.f = x; b.f = y;
    return (a.u >> 16) | (b.u & 0xffff0000u);
}

// async 16B global->LDS (DMA, no VGPR round-trip)
__device__ inline void gl_lds16(const u16* g, u16* l) {
    __builtin_amdgcn_global_load_lds(
        (const __attribute__((address_space(1))) unsigned int*)g,
        (__attribute__((address_space(3))) unsigned int*)l, 16, 0, 0);
}

// ---------------- prep: fused x-cast (z==4) + weight cast/transpose (z<4) ----------------
__global__ __launch_bounds__(256) void prep_k(const float* __restrict__ x,
                                              const float* __restrict__ Wq,
                                              const float* __restrict__ Wk,
                                              const float* __restrict__ Wv,
                                              const float* __restrict__ Wo,
                                              u16* __restrict__ xb,
                                              u16* __restrict__ WT) {
    int tid = threadIdx.x;
    if (blockIdx.z == 4) {   // cast x: 1024 blocks x 1024 float4
        int bid = blockIdx.y * 32 + blockIdx.x;
#pragma unroll
        for (int k = 0; k < 4; k++) {
            int i = bid * 1024 + k * 256 + tid;
            float4v v = ((const float4v*)x)[i];
            ushort4 o;
            o.x = f2bf(v[0]); o.y = f2bf(v[1]); o.z = f2bf(v[2]); o.w = f2bf(v[3]);
            ((ushort4*)xb)[i] = o;
        }
        return;
    }
    __shared__ u16 t[32][33];
    int wsel = blockIdx.z;
    const float* W = (wsel == 0) ? Wq : (wsel == 1) ? Wk : (wsel == 2) ? Wv : Wo;
    u16* o = WT + (size_t)wsel * DD * DD;
    int k0 = blockIdx.y * 32, n0 = blockIdx.x * 32;
    int tx = tid & 31, ty = tid >> 5;   // 32 x 8
#pragma unroll
    for (int i = 0; i < 4; i++) {
        int k = ty + i * 8;
        t[k][tx] = f2bf(W[(size_t)(k0 + k) * DD + n0 + tx]);
    }
    __syncthreads();
#pragma unroll
    for (int i = 0; i < 4; i++) {
        int n = ty + i * 8;
        o[(size_t)(n0 + n) * DD + k0 + tx] = t[tx][n];
    }
}

// ---------------- GEMM: global_load_lds staging (m97 structure) ----------------
template <int MODE, int TM, int TN, int BK>
__global__ __launch_bounds__(256) void gemm_k(const u16* __restrict__ A,
                                              const u16* __restrict__ WT0,
                                              void* __restrict__ outp) {
    const int K = DD;
    const int MT = TM / 32, NT = TN / 32;
    const int NS = (TM + TN) * (BK / 8) / 256;
    const int CPR = BK / 8;

    int z = blockIdx.z;
    const u16* WT = WT0 + (size_t)z * DD * DD;
    int n0 = blockIdx.x * TN, m0 = blockIdx.y * TM;

    __shared__ u16 S[(TM + TN) * BK];

    int tid = threadIdx.x;
    int lane = tid & 63, w = tid >> 6;
    int wm = (w >> 1) * (TM / 2), wn = (w & 1) * (TN / 2);
    int quad = lane >> 4, l16 = lane & 15;

    const u16* gp[NS];
    u16* lp[NS];
#pragma unroll
    for (int j = 0; j < NS; j++) {
        int cid = tid + j * 256;
        int r = cid / CPR, c = cid % CPR;
        lp[j] = S + (size_t)cid * 8;                      // linear LDS dest
        gp[j] = (r < TM ? A + (size_t)(m0 + r) * K
                        : WT + (size_t)(n0 + r - TM) * K) + ((c ^ (r & 7)) * 8);
    }
    int swz = l16 & 7;

    float4v acc[MT][NT];
#pragma unroll
    for (int i = 0; i < MT; i++)
#pragma unroll
        for (int j = 0; j < NT; j++) acc[i][j] = (float4v)(0.0f);

    const int NK = K / BK;
#pragma unroll 1
    for (int ki = 0; ki < NK; ki++) {
        __syncthreads();    // prev compute's S reads done
#pragma unroll
        for (int j = 0; j < NS; j++)
            gl_lds16(gp[j] + ki * BK, lp[j]);
        __syncthreads();    // barrier drain (vmcnt 0) publishes S

#pragma unroll
        for (int ks = 0; ks < BK / 32; ks++) {
            int cq = ((ks * 4 + quad) ^ swz) * 8;
            short8 a[MT], b[NT];
#pragma unroll
            for (int mt = 0; mt < MT; mt++)
                a[mt] = *(const short8*)&S[(wm + mt * 16 + l16) * BK + cq];
#pragma unroll
            for (int nt = 0; nt < NT; nt++)
                b[nt] = *(const short8*)&S[(TM + wn + nt * 16 + l16) * BK + cq];
#pragma unroll
            for (int mt = 0; mt < MT; mt++)
#pragma unroll
                for (int nt = 0; nt < NT; nt++)
                    acc[mt][nt] = __builtin_amdgcn_mfma_f32_16x16x32_bf16(
                        a[mt], b[nt], acc[mt][nt], 0, 0, 0);
        }
    }

#pragma unroll
    for (int mt = 0; mt < MT; mt++) {
#pragma unroll
        for (int nt = 0; nt < NT; nt++) {
#pragma unroll
            for (int r = 0; r < 4; r++) {
                int m = m0 + wm + mt * 16 + quad * 4 + r;
                int n = n0 + wn + nt * 16 + l16;
                float v = acc[mt][nt][r];
                if constexpr (MODE == 0) {
                    int bb = m >> 11, t = m & 2047;
                    int h = n >> 6, dh = n & 63;
                    size_t idx;
                    if (z == 2)   // V stored transposed: (b,h,dh,t)
                        idx = (((size_t)2 * BB * HH + bb * HH + h) * DHD + dh) * TT + t;
                    else
                        idx = (((size_t)z * BB * HH + bb * HH + h) * TT + t) * DHD + dh;
                    ((u16*)outp)[idx] = f2bf(v);
                } else {
                    ((float*)outp)[(size_t)m * DD + n] = v;
                }
            }
        }
    }
}

// ---------------- flash attention: 32x32 MFMA, V direct-from-L2, in-reg P ----------------
// One block per (bh, 128 q-rows). 8 waves = 4 q-blocks(32 rows) x 2 kv-groups.
// R6 change: V is NOT staged in LDS. R5 counters showed the LDS pipe is the
// largest per-round resource (~3000 cyc/round-pair: 256KB frag reads at
// 85 B/cyc + staging + 2.2M conflict cycles), and the 4 q-waves of a group
// read IDENTICAL V frags (8KB tile read as 32KB). V^T layout makes the PV
// B-frag a plain coalesced 16B/lane global load (row d=l31(+32), col
// 128jt+64g+c*8, no swizzle) -> issued right after the barrier (T14
// issue-early), consumed after QK^T+softmax (~600cyc) hides L2 latency.
// Demand 51 B/cyc/CU << L2 share; 4-wave reuse L1-hits (tile < 32KB L1).
// LDS 64->33KB, staging writes halve, K path/swizzle/P path byte-identical.
__global__ __launch_bounds__(512, 4) void attn_k(const u16* __restrict__ QKV,
                                                 u16* __restrict__ AO) {
    const u16* Q  = QKV;
    const u16* Kp = QKV + (size_t)MM * DD;
    const u16* Vp = QKV + (size_t)2 * MM * DD;   // V^T: per head [DHD][TT]
    int bx = blockIdx.x, by = blockIdx.y;
    int bh = bx;
    int t_ = by & 7, s_ = by >> 3;
    int qt = ((bx ^ s_) & 1) ? (15 - t_) : t_;   // dual-pairing-balanced
    size_t hoff = (size_t)bh * TT * DHD;

    __shared__ u16 Ks[2][2][64 * 64];    // 32 KB [dbuf][tile]
    __shared__ float Lfs[4 * 64];        // 1 KB rowsum combine scratch

    int tid = threadIdx.x;
    int lane = tid & 63, wv = tid >> 6;
    int g = wv >> 2, w4 = wv & 3;        // kv-group, q 32-row block
    int l31 = lane & 31, hi = lane >> 5;
    int swz = l31 & 7;

    // K staging: one 16B chunk per thread per 64x64 tile (identical to verified)
    int sr = tid >> 3, sc = tid & 7;
    int sl = sr * 64 + ((sc ^ (sr & 7)) * 8);
    const u16* gK = Kp + hoff + (size_t)sr * DHD + sc * 8;

    // V frag bases: rows d = l31 and 32+l31; col = 128*jt + 64*g + c*8, c=hi+2*kt2
    const u16* gv0 = Vp + hoff + (size_t)l31 * TT + (size_t)g * 64 + hi * 8;
    const u16* gv1 = gv0 + (size_t)32 * TT;

    // Q B-frags direct from global (col=q=lane&31, k=8*hi+16*kt+e), scaled
    const float qscale = 0.125f * 1.4426950408889634f;
    int q0 = qt * 128;
    short8 qB[4];
    {
        const u16* gq = Q + hoff + (size_t)(q0 + w4 * 32 + l31) * DHD + hi * 8;
#pragma unroll
        for (int kt = 0; kt < 4; kt++) {
            short8 v = *(const short8*)(gq + 16 * kt);
            short8 sv;
#pragma unroll
            for (int e = 0; e < 8; e++) sv[e] = (short)f2bf(bf2f((u16)v[e]) * qscale);
            qB[kt] = sv;
        }
    }

    // prefetch round-0 K tiles
    short8 prK[2];
    prK[0] = *(const short8*)gK;
    prK[1] = *(const short8*)(gK + (size_t)64 * DHD);

    const int NR = qt + 1;   // round jt stages kv tiles 2jt, 2jt+1

    f32x16 o0 = (f32x16)(0.0f), o1 = (f32x16)(0.0f);
    float lr = 0.0f;

#pragma unroll 1
    for (int jt = 0; jt < NR; jt++) {
        int db = jt & 1;
#pragma unroll
        for (int tt = 0; tt < 2; tt++)
            *(short8*)&Ks[db][tt][sl] = prK[tt];
        __syncthreads();

        if (jt + 1 < NR) {
            size_t nj = (size_t)(jt + 1) * 128;
            prK[0] = *(const short8*)(gK + nj * DHD);
            prK[1] = *(const short8*)(gK + (nj + 64) * DHD);
        }

        // issue V frag loads now (T14); consumed after QK^T + softmax
        short8 bvr0[4], bvr1[4];
        {
            const u16* v0 = gv0 + (size_t)jt * 128;
            const u16* v1 = gv1 + (size_t)jt * 128;
#pragma unroll
            for (int kt2 = 0; kt2 < 4; kt2++) {
                bvr0[kt2] = *(const short8*)(v0 + kt2 * 16);
                bvr1[kt2] = *(const short8*)(v1 + kt2 * 16);
            }
        }

        // ---- S^T = K.Q^T (own tile g): lane&31 = q, regs = kv ----
        f32x16 s0 = (f32x16)(0.0f), s1 = (f32x16)(0.0f);
#pragma unroll
        for (int kt = 0; kt < 4; kt++) {
            int ch = ((hi + 2 * kt) ^ swz) * 8;
            short8 ak0 = *(const short8*)&Ks[db][g][l31 * 64 + ch];
            short8 ak1 = *(const short8*)&Ks[db][g][(32 + l31) * 64 + ch];
            s0 = __builtin_amdgcn_mfma_f32_32x32x16_bf16(ak0, qB[kt], s0, 0, 0, 0);
            s1 = __builtin_amdgcn_mfma_f32_32x32x16_bf16(ak1, qB[kt], s1, 0, 0, 0);
        }

        if (jt == qt) {   // diagonal round: mask kv > q (both tiles partial)
            int lim = w4 * 32 + l31 - g * 64;
#pragma unroll
            for (int r = 0; r < 16; r++) {
                int kvl = (r & 3) + 8 * (r >> 2) + 4 * hi;
                if (kvl > lim) s0[r] = -30000.0f;
                if (32 + kvl > lim) s1[r] = -30000.0f;
            }
        }

        // p = exp2(s) in place; rowsum
#pragma unroll
        for (int r = 0; r < 16; r++) {
            s0[r] = __builtin_amdgcn_exp2f(s0[r]);
            s1[r] = __builtin_amdgcn_exp2f(s1[r]);
            lr += s0[r] + s1[r];
        }

        // ---- build PV A-frags in-register (kv chunk = 16*kt2 + 8*hi + e) ----
        short8 pa[4];
#pragma unroll
        for (int kt2 = 0; kt2 < 4; kt2++) {
            f32x16 ps = (kt2 < 2) ? s0 : s1;
            const int base = 8 * (kt2 & 1);
            float e0 = ps[base + 0], e1 = ps[base + 1];
            float e2 = ps[base + 2], e3 = ps[base + 3];
            float e4 = ps[base + 4], e5 = ps[base + 5];
            float e6 = ps[base + 6], e7 = ps[base + 7];
            unsigned lA = packtr(e0, e1), lB = packtr(e2, e3);
            unsigned hA = packtr(e4, e5), hB = packtr(e6, e7);
            unsigned wA = hi ? hA : lA, wB = hi ? hB : lB;   // own half (t=hi)
            unsigned sA = hi ? lA : hA, sB = hi ? lB : hB;   // for partner (t=hi^1)
            unsigned rA = (unsigned)__shfl_xor((int)sA, 32);
            unsigned rB = (unsigned)__shfl_xor((int)sB, 32);
            union { unsigned w[4]; short8 v; } u;
            u.w[0] = hi ? rA : wA; u.w[1] = hi ? rB : wB;
            u.w[2] = hi ? wA : rA; u.w[3] = hi ? wB : rB;
            pa[kt2] = u.v;
        }

        // ---- PV: o(32q x 64d), B = V^T rows d (from regs), k chunk = hi+2*kt2 ----
#pragma unroll
        for (int kt2 = 0; kt2 < 4; kt2++) {
            o0 = __builtin_amdgcn_mfma_f32_32x32x16_bf16(pa[kt2], bvr0[kt2], o0, 0, 0, 0);
            o1 = __builtin_amdgcn_mfma_f32_32x32x16_bf16(pa[kt2], bvr1[kt2], o1, 0, 0, 0);
        }
    }

    // ---- combine group partials (sums are linear), normalize, store ----
    __syncthreads();
    float* Of = (float*)&Ks[0][0][0];    // [w4][dt][r][lane] = 32 KB (all of Ks)
    if (g == 1) {
#pragma unroll
        for (int r = 0; r < 16; r++) {
            Of[((w4 * 2 + 0) * 16 + r) * 64 + lane] = o0[r];
            Of[((w4 * 2 + 1) * 16 + r) * 64 + lane] = o1[r];
        }
        Lfs[w4 * 64 + lane] = lr;
    }
    __syncthreads();
    if (g == 0) {
#pragma unroll
        for (int r = 0; r < 16; r++) {
            o0[r] += Of[((w4 * 2 + 0) * 16 + r) * 64 + lane];
            o1[r] += Of[((w4 * 2 + 1) * 16 + r) * 64 + lane];
        }
        lr += Lfs[w4 * 64 + lane];

        float rs = lr + __shfl_xor(lr, 32);   // full rowsum for q = lane&31

        int b = bh >> 4, h = bh & 15;
#pragma unroll
        for (int r = 0; r < 16; r++) {
            int qlc = (r & 3) + 8 * (r >> 2) + 4 * hi;   // q row of this reg
            float ri = 1.0f / __shfl(rs, qlc);
            int q = q0 + w4 * 32 + qlc;
            size_t rb = (size_t)(b * TT + q) * DD + h * 64 + l31;
            AO[rb]      = f2bf(o0[r] * ri);
            AO[rb + 32] = f2bf(o1[r] * ri);
        }
    }
}

extern "C" void kernel_launch(void* const* d_in, const int* in_sizes, int n_in,
                              void* d_out, int out_size, void* d_ws, size_t ws_size,
                              hipStream_t stream) {
    const float* x  = (const float*)d_in[0];
    const float* Wq = (const float*)d_in[1];
    const float* Wk = (const float*)d_in[2];
    const float* Wv = (const float*)d_in[3];
    const float* Wo = (const float*)d_in[4];

    u16* xb  = (u16*)d_ws;                       // 8 MB  : x in bf16
    u16* WT  = xb + (size_t)MM * DD;             // 8 MB  : 4 transposed weights bf16
    u16* QKV = WT + (size_t)4 * DD * DD;         // 24 MB : Q,K (b,h,t,dh) + V^T (b,h,dh,t)
    u16* AO  = QKV + (size_t)3 * MM * DD;        // 8 MB  : attention out (B,T,D) bf16
    float* out = (float*)d_out;

    prep_k<<<dim3(32, 32, 5), 256, 0, stream>>>(x, Wq, Wk, Wv, Wo, xb, WT);
    gemm_k<0, 128, 128, 64><<<dim3(DD / 128, MM / 128, 3), 256, 0, stream>>>(xb, WT, QKV);
    attn_k<<<dim3(32, 16), 512, 0, stream>>>(QKV, AO);
    gemm_k<1, 64, 128, 64><<<dim3(DD / 128, MM / 64, 1), 256, 0, stream>>>(AO, WT + (size_t)3 * DD * DD, out);
}

// Round 7
// 208.526 us; speedup vs baseline: 1.0989x; 1.0989x over previous
//
#include <hip/hip_runtime.h>

#define BB 2
#define TT 2048
#define DD 1024
#define HH 16
#define DHD 64
#define MM (BB*TT)   // 4096

typedef __attribute__((ext_vector_type(8))) short short8;
typedef __attribute__((ext_vector_type(4))) float float4v;
typedef unsigned short u16;

__device__ inline float bf2f(u16 u) {
    union { unsigned int i; float f; } v;
    v.i = ((unsigned int)u) << 16;
    return v.f;
}
__device__ inline u16 f2bf(float f) {
    union { float f; unsigned int i; } v;
    v.f = f;
    unsigned int x = v.i;
    unsigned int r = (x + 0x7fffu + ((x >> 16) & 1u)) >> 16;
    return (u16)r;
}

// async 16B global->LDS (DMA, no VGPR round-trip)
__device__ inline void gl_lds16(const u16* g, u16* l) {
    __builtin_amdgcn_global_load_lds(
        (const __attribute__((address_space(1))) unsigned int*)g,
        (__attribute__((address_space(3))) unsigned int*)l, 16, 0, 0);
}

// ---------------- prep: fused x-cast (z==4) + weight cast/transpose (z<4) ----------------
__global__ __launch_bounds__(256) void prep_k(const float* __restrict__ x,
                                              const float* __restrict__ Wq,
                                              const float* __restrict__ Wk,
                                              const float* __restrict__ Wv,
                                              const float* __restrict__ Wo,
                                              u16* __restrict__ xb,
                                              u16* __restrict__ WT) {
    int tid = threadIdx.x;
    if (blockIdx.z == 4) {   // cast x: 1024 blocks x 1024 float4
        int bid = blockIdx.y * 32 + blockIdx.x;
#pragma unroll
        for (int k = 0; k < 4; k++) {
            int i = bid * 1024 + k * 256 + tid;
            float4v v = ((const float4v*)x)[i];
            ushort4 o;
            o.x = f2bf(v[0]); o.y = f2bf(v[1]); o.z = f2bf(v[2]); o.w = f2bf(v[3]);
            ((ushort4*)xb)[i] = o;
        }
        return;
    }
    __shared__ u16 t[32][33];
    int wsel = blockIdx.z;
    const float* W = (wsel == 0) ? Wq : (wsel == 1) ? Wk : (wsel == 2) ? Wv : Wo;
    u16* o = WT + (size_t)wsel * DD * DD;
    int k0 = blockIdx.y * 32, n0 = blockIdx.x * 32;
    int tx = tid & 31, ty = tid >> 5;   // 32 x 8
#pragma unroll
    for (int i = 0; i < 4; i++) {
        int k = ty + i * 8;
        t[k][tx] = f2bf(W[(size_t)(k0 + k) * DD + n0 + tx]);
    }
    __syncthreads();
#pragma unroll
    for (int i = 0; i < 4; i++) {
        int n = ty + i * 8;
        o[(size_t)(n0 + n) * DD + k0 + tx] = t[tx][n];
    }
}

// ---------------- GEMM: global_load_lds staging (m97 structure) ----------------
template <int MODE, int TM, int TN, int BK>
__global__ __launch_bounds__(256) void gemm_k(const u16* __restrict__ A,
                                              const u16* __restrict__ WT0,
                                              void* __restrict__ outp) {
    const int K = DD;
    const int MT = TM / 32, NT = TN / 32;
    const int NS = (TM + TN) * (BK / 8) / 256;
    const int CPR = BK / 8;

    int z = blockIdx.z;
    const u16* WT = WT0 + (size_t)z * DD * DD;
    int n0 = blockIdx.x * TN, m0 = blockIdx.y * TM;

    __shared__ u16 S[(TM + TN) * BK];

    int tid = threadIdx.x;
    int lane = tid & 63, w = tid >> 6;
    int wm = (w >> 1) * (TM / 2), wn = (w & 1) * (TN / 2);
    int quad = lane >> 4, l16 = lane & 15;

    const u16* gp[NS];
    u16* lp[NS];
#pragma unroll
    for (int j = 0; j < NS; j++) {
        int cid = tid + j * 256;
        int r = cid / CPR, c = cid % CPR;
        lp[j] = S + (size_t)cid * 8;                      // linear LDS dest
        gp[j] = (r < TM ? A + (size_t)(m0 + r) * K
                        : WT + (size_t)(n0 + r - TM) * K) + ((c ^ (r & 7)) * 8);
    }
    int swz = l16 & 7;

    float4v acc[MT][NT];
#pragma unroll
    for (int i = 0; i < MT; i++)
#pragma unroll
        for (int j = 0; j < NT; j++) acc[i][j] = (float4v)(0.0f);

    const int NK = K / BK;
#pragma unroll 1
    for (int ki = 0; ki < NK; ki++) {
        __syncthreads();    // prev compute's S reads done
#pragma unroll
        for (int j = 0; j < NS; j++)
            gl_lds16(gp[j] + ki * BK, lp[j]);
        __syncthreads();    // barrier drain (vmcnt 0) publishes S

#pragma unroll
        for (int ks = 0; ks < BK / 32; ks++) {
            int cq = ((ks * 4 + quad) ^ swz) * 8;
            short8 a[MT], b[NT];
#pragma unroll
            for (int mt = 0; mt < MT; mt++)
                a[mt] = *(const short8*)&S[(wm + mt * 16 + l16) * BK + cq];
#pragma unroll
            for (int nt = 0; nt < NT; nt++)
                b[nt] = *(const short8*)&S[(TM + wn + nt * 16 + l16) * BK + cq];
#pragma unroll
            for (int mt = 0; mt < MT; mt++)
#pragma unroll
                for (int nt = 0; nt < NT; nt++)
                    acc[mt][nt] = __builtin_amdgcn_mfma_f32_16x16x32_bf16(
                        a[mt], b[nt], acc[mt][nt], 0, 0, 0);
        }
    }

#pragma unroll
    for (int mt = 0; mt < MT; mt++) {
#pragma unroll
        for (int nt = 0; nt < NT; nt++) {
#pragma unroll
            for (int r = 0; r < 4; r++) {
                int m = m0 + wm + mt * 16 + quad * 4 + r;
                int n = n0 + wn + nt * 16 + l16;
                float v = acc[mt][nt][r];
                if constexpr (MODE == 0) {
                    int bb = m >> 11, t = m & 2047;
                    int h = n >> 6, dh = n & 63;
                    size_t idx;
                    if (z == 2)   // V stored transposed: (b,h,dh,t)
                        idx = (((size_t)2 * BB * HH + bb * HH + h) * DHD + dh) * TT + t;
                    else
                        idx = (((size_t)z * BB * HH + bb * HH + h) * TT + t) * DHD + dh;
                    ((u16*)outp)[idx] = f2bf(v);
                } else {
                    ((float*)outp)[(size_t)m * DD + n] = v;
                }
            }
        }
    }
}

// ---------------- flash attention: split-KV (verified R0 structure), V direct ----------------
// Identical to the proven 40us kernel EXCEPT: V is not staged in LDS. The PV
// B-frag address is the de-swizzled equivalent of the old LDS read:
// V^T[d=ct*16+l16][tj*64 + quad*8 (+32)] -- same fragment content, loaded
// straight from global (head's V = 256KB, L2-resident; 4 waves/group share
// frags via L1). All 8 loads issued right after the barrier (T14); consumed
// after QK^T+softmax. Removes per-round: 16KB V staging writes + 16KB/wave
// V LDS reads. LDS 80->48KB. VGPR ~64->~100, default bounds (no spill).
__global__ __launch_bounds__(512) void attn_k(const u16* __restrict__ QKV,
                                              u16* __restrict__ AO) {
    const u16* Q  = QKV;
    const u16* Kp = QKV + (size_t)MM * DD;
    const u16* Vp = QKV + (size_t)2 * MM * DD;   // V^T: per head [DHD][TT]
    int bh = blockIdx.x;
    int qt = 31 - blockIdx.y;
    size_t hoff = (size_t)bh * TT * DHD;

    __shared__ u16 Ks[2][2][64 * 64];    // 32 KB [dbuf][group-tile]
    __shared__ u16 Ps[8][16 * 64];       // 16 KB per-wave P scratch; Q staged in Ps[0..3]

    int tid = threadIdx.x;
    int lane = tid & 63, wv = tid >> 6;      // 8 waves
    int g = wv >> 2, w4 = wv & 3;            // KV-split group, 16-row q block
    int quad = lane >> 4, l16 = lane & 15;
    int cxs = l16 & 7;

    // K staging: one 16B chunk per thread per 64x64 tile
    int sr = tid >> 3, sc = tid & 7;
    int sl = sr * 64 + ((sc ^ (sr & 7)) * 8);
    const u16* gK = Kp + hoff + (size_t)sr * DHD + sc * 8;

    // V frag base: row d = ct*16+l16 (stride TT), col tj*64 + quad*8 (+32)
    const u16* gVf = Vp + hoff + (size_t)l16 * TT + quad * 8;

    u16* Qstage = &Ps[0][0];   // 8 KB

    // stage Q tile qt, scaled by (1/sqrt(DH)) * log2(e)
    const float qscale = 0.125f * 1.4426950408889634f;
    int q0 = qt * 64;
    {
        short8 v = *(const short8*)(Q + hoff + (size_t)(q0 + sr) * DHD + sc * 8);
        short8 sv;
#pragma unroll
        for (int e = 0; e < 8; e++) sv[e] = (short)f2bf(bf2f((u16)v[e]) * qscale);
        *(short8*)&Qstage[sl] = sv;
    }

    // prefetch round-0 K tiles (0 and 1)
    short8 prK[2];
    prK[0] = *(const short8*)gK;
    prK[1] = *(const short8*)(gK + (size_t)64 * DHD);

    __syncthreads();   // Q staged
    int fr = w4 * 16 + l16;   // my q-row (local)
    short8 aq0 = *(const short8*)&Qstage[fr * 64 + ((quad ^ cxs) * 8)];
    short8 aq1 = *(const short8*)&Qstage[fr * 64 + (((4 + quad) ^ cxs) * 8)];

    int NR = (qt >> 1) + 1;   // rounds (2 tiles staged per round)

    float4v o[4];
#pragma unroll
    for (int i = 0; i < 4; i++) o[i] = (float4v)(0.0f);
    float lr = 0.0f;

#pragma unroll 1
    for (int jt = 0; jt < NR; jt++) {
        int db = jt & 1;
#pragma unroll
        for (int tt = 0; tt < 2; tt++)
            *(short8*)&Ks[db][tt][sl] = prK[tt];
        __syncthreads();   // publishes round db; drains Q frag reads on jt==0

        if (jt + 1 < NR) {   // prefetch next round's two K tiles
            size_t nj = (size_t)(jt + 1) * 128;
            prK[0] = *(const short8*)(gK + nj * DHD);
            prK[1] = *(const short8*)(gK + (nj + 64) * DHD);
        }

        int tj = 2 * jt + g;   // my group's tile this round
        if (tj <= qt) {
            // issue V frag loads now (T14); consumed after QK^T + softmax
            short8 bv0[4], bv1[4];
            {
                const u16* gv = gVf + (size_t)tj * 64;
#pragma unroll
                for (int ct = 0; ct < 4; ct++) {
                    bv0[ct] = *(const short8*)(gv + (size_t)ct * 16 * TT);
                    bv1[ct] = *(const short8*)(gv + (size_t)ct * 16 * TT + 32);
                }
            }

            // S^T (64 kv x 16 q per wave) = K·Q^T
            float4v s[4];
#pragma unroll
            for (int ct = 0; ct < 4; ct++) {
                int kr = (ct * 16 + l16) * 64;
                short8 ak0 = *(const short8*)&Ks[db][g][kr + ((quad ^ cxs) * 8)];
                short8 ak1 = *(const short8*)&Ks[db][g][kr + (((4 + quad) ^ cxs) * 8)];
                float4v sv = (float4v)(0.0f);
                sv = __builtin_amdgcn_mfma_f32_16x16x32_bf16(ak0, aq0, sv, 0, 0, 0);
                sv = __builtin_amdgcn_mfma_f32_16x16x32_bf16(ak1, aq1, sv, 0, 0, 0);
                s[ct] = sv;   // lane: kv = ct*16+quad*4+r, q = fr
            }

            if (tj == qt) {   // diagonal tile: mask kv > q (local coords)
                int ql = w4 * 16 + l16;
#pragma unroll
                for (int ct = 0; ct < 4; ct++)
#pragma unroll
                    for (int r = 0; r < 4; r++) {
                        int kvl = ct * 16 + quad * 4 + r;
                        if (kvl > ql) s[ct][r] = -30000.0f;
                    }
            }

            // p = v_exp_f32(s); P write (C->A layout) swizzled 8B stores
#pragma unroll
            for (int ct = 0; ct < 4; ct++) {
                float p0 = __builtin_amdgcn_exp2f(s[ct][0]);
                float p1 = __builtin_amdgcn_exp2f(s[ct][1]);
                float p2 = __builtin_amdgcn_exp2f(s[ct][2]);
                float p3 = __builtin_amdgcn_exp2f(s[ct][3]);
                lr += (p0 + p1) + (p2 + p3);
                union { float f; unsigned u; } c0, c1, c2, c3;
                c0.f = p0; c1.f = p1; c2.f = p2; c3.f = p3;
                ushort4 pw;
                pw.x = (u16)(c0.u >> 16);
                pw.y = (u16)(c1.u >> 16);
                pw.z = (u16)(c2.u >> 16);
                pw.w = (u16)(c3.u >> 16);
                int chnk = (ct * 2 + (quad >> 1)) ^ cxs;
                *(ushort4*)&Ps[wv][l16 * 64 + chnk * 8 + (quad & 1) * 4] = pw;
            }

            short8 ap0 = *(const short8*)&Ps[wv][l16 * 64 + ((quad ^ cxs) * 8)];
            short8 ap1 = *(const short8*)&Ps[wv][l16 * 64 + (((4 + quad) ^ cxs) * 8)];
#pragma unroll
            for (int ct = 0; ct < 4; ct++) {
                o[ct] = __builtin_amdgcn_mfma_f32_16x16x32_bf16(ap0, bv0[ct], o[ct], 0, 0, 0);
                o[ct] = __builtin_amdgcn_mfma_f32_16x16x32_bf16(ap1, bv1[ct], o[ct], 0, 0, 0);
            }
        }
    }

    // combine group partials: group 1 -> LDS, group 0 adds (sums are linear)
    __syncthreads();   // last round's Ks/Ps reads complete before reuse
    float* Of = (float*)&Ks[0][0][0];    // [w4][ct][r][lane] = 16 KB
    float* Lf = (float*)&Ps[0][0];       // [w4][lane] = 1 KB
    if (g == 1) {
#pragma unroll
        for (int ct = 0; ct < 4; ct++)
#pragma unroll
            for (int r = 0; r < 4; r++)
                Of[(((w4 * 4 + ct) * 4 + r) * 64) + lane] = o[ct][r];
        Lf[w4 * 64 + lane] = lr;
    }
    __syncthreads();
    if (g == 0) {
#pragma unroll
        for (int ct = 0; ct < 4; ct++)
#pragma unroll
            for (int r = 0; r < 4; r++)
                o[ct][r] += Of[(((w4 * 4 + ct) * 4 + r) * 64) + lane];
        lr += Lf[w4 * 64 + lane];

        // reduce row sums across quads (lane holds q = w4*16 + l16)
        float rs = lr;
        rs += __shfl_xor(rs, 16);
        rs += __shfl_xor(rs, 32);
        int gbase = lane & 48;
        float rinv[4];
#pragma unroll
        for (int r = 0; r < 4; r++)
            rinv[r] = 1.0f / __shfl(rs, gbase + quad * 4 + r);

        int b = bh >> 4, h = bh & 15;
#pragma unroll
        for (int ct = 0; ct < 4; ct++) {
#pragma unroll
            for (int r = 0; r < 4; r++) {
                int q = q0 + w4 * 16 + quad * 4 + r;
                int d = h * 64 + ct * 16 + l16;
                AO[(size_t)(b * TT + q) * DD + d] = f2bf(o[ct][r] * rinv[r]);
            }
        }
    }
}

extern "C" void kernel_launch(void* const* d_in, const int* in_sizes, int n_in,
                              void* d_out, int out_size, void* d_ws, size_t ws_size,
                              hipStream_t stream) {
    const float* x  = (const float*)d_in[0];
    const float* Wq = (const float*)d_in[1];
    const float* Wk = (const float*)d_in[2];
    const float* Wv = (const float*)d_in[3];
    const float* Wo = (const float*)d_in[4];

    u16* xb  = (u16*)d_ws;                       // 8 MB  : x in bf16
    u16* WT  = xb + (size_t)MM * DD;             // 8 MB  : 4 transposed weights bf16
    u16* QKV = WT + (size_t)4 * DD * DD;         // 24 MB : Q,K (b,h,t,dh) + V^T (b,h,dh,t)
    u16* AO  = QKV + (size_t)3 * MM * DD;        // 8 MB  : attention out (B,T,D) bf16
    float* out = (float*)d_out;

    prep_k<<<dim3(32, 32, 5), 256, 0, stream>>>(x, Wq, Wk, Wv, Wo, xb, WT);
    gemm_k<0, 128, 128, 64><<<dim3(DD / 128, MM / 128, 3), 256, 0, stream>>>(xb, WT, QKV);
    attn_k<<<dim3(32, 32), 512, 0, stream>>>(QKV, AO);
    gemm_k<1, 64, 128, 64><<<dim3(DD / 128, MM / 64, 1), 256, 0, stream>>>(AO, WT + (size_t)3 * DD * DD, out);
}

// Round 8
// 188.630 us; speedup vs baseline: 1.2148x; 1.1055x over previous
//
#include <hip/hip_runtime.h>

#define BB 2
#define TT 2048
#define DD 1024
#define HH 16
#define DHD 64
#define MM (BB*TT)   // 4096

typedef __attribute__((ext_vector_type(8))) short short8;
typedef __attribute__((ext_vector_type(4))) float float4v;
typedef unsigned short u16;

__device__ inline float bf2f(u16 u) {
    union { unsigned int i; float f; } v;
    v.i = ((unsigned int)u) << 16;
    return v.f;
}
__device__ inline u16 f2bf(float f) {
    union { float f; unsigned int i; } v;
    v.f = f;
    unsigned int x = v.i;
    unsigned int r = (x + 0x7fffu + ((x >> 16) & 1u)) >> 16;
    return (u16)r;
}

// async 16B global->LDS (DMA, no VGPR round-trip)
__device__ inline void gl_lds16(const u16* g, u16* l) {
    __builtin_amdgcn_global_load_lds(
        (const __attribute__((address_space(1))) unsigned int*)g,
        (__attribute__((address_space(3))) unsigned int*)l, 16, 0, 0);
}

// ---------------- prep: fused x-cast (z==4) + weight cast/transpose (z<4) ----------------
__global__ __launch_bounds__(256) void prep_k(const float* __restrict__ x,
                                              const float* __restrict__ Wq,
                                              const float* __restrict__ Wk,
                                              const float* __restrict__ Wv,
                                              const float* __restrict__ Wo,
                                              u16* __restrict__ xb,
                                              u16* __restrict__ WT) {
    int tid = threadIdx.x;
    if (blockIdx.z == 4) {   // cast x: 1024 blocks x 1024 float4
        int bid = blockIdx.y * 32 + blockIdx.x;
#pragma unroll
        for (int k = 0; k < 4; k++) {
            int i = bid * 1024 + k * 256 + tid;
            float4v v = ((const float4v*)x)[i];
            ushort4 o;
            o.x = f2bf(v[0]); o.y = f2bf(v[1]); o.z = f2bf(v[2]); o.w = f2bf(v[3]);
            ((ushort4*)xb)[i] = o;
        }
        return;
    }
    __shared__ u16 t[32][33];
    int wsel = blockIdx.z;
    const float* W = (wsel == 0) ? Wq : (wsel == 1) ? Wk : (wsel == 2) ? Wv : Wo;
    u16* o = WT + (size_t)wsel * DD * DD;
    int k0 = blockIdx.y * 32, n0 = blockIdx.x * 32;
    int tx = tid & 31, ty = tid >> 5;   // 32 x 8
#pragma unroll
    for (int i = 0; i < 4; i++) {
        int k = ty + i * 8;
        t[k][tx] = f2bf(W[(size_t)(k0 + k) * DD + n0 + tx]);
    }
    __syncthreads();
    // vectorized write-back: lane = (row n, 4-wide k chunk) -> ushort4 store
    int n = tid >> 3, kc = tid & 7;
    ushort4 w4v;
    w4v.x = t[kc * 4 + 0][n];
    w4v.y = t[kc * 4 + 1][n];
    w4v.z = t[kc * 4 + 2][n];
    w4v.w = t[kc * 4 + 3][n];
    *(ushort4*)&o[(size_t)(n0 + n) * DD + k0 + kc * 4] = w4v;
}

// ---------------- QKV GEMM: 256x256 tile, 2-slot dbuf, 1 barrier per K-tile ----------------
// T3's "minimum 2-phase" discipline: stage(kt+1 -> slot^1) issued BEFORE
// compute(kt, slot), single __syncthreads per K-tile (its vmcnt0 drain is
// ~free: loads had ~2000cyc of compute to land). Race-safe: slot^1's last
// readers finished at the PREVIOUS barrier; slot's stage drained at it too.
// 64 wave-MFMAs per barrier (4x the 128^2 kernel's amortization). Same
// verified XOR-swizzle family (linear LDS dest + pre-swizzled global src).
__global__ __launch_bounds__(512, 2) void gemmq_k(const u16* __restrict__ A,
                                                  const u16* __restrict__ WT0,
                                                  u16* __restrict__ outp) {
    const int K = DD;
    int z = blockIdx.z;
    const u16* WT = WT0 + (size_t)z * DD * DD;
    int n0 = blockIdx.x * 256, m0 = blockIdx.y * 256;

    __shared__ u16 S[2 * 512 * 64];   // 128 KB: 2 slots x (A 256 + B 256 rows) x BK=64

    int tid = threadIdx.x;
    int lane = tid & 63, w = tid >> 6;          // 8 waves: 2(M) x 4(N)
    int wm = (w >> 2) * 128, wn = (w & 3) * 64; // per-wave 128x64 output
    int quad = lane >> 4, l16 = lane & 15;
    int swz = l16 & 7;

    // staging: 8 chunks of 16B per thread per K-tile (A rows 0..255, B rows 256..511)
    const u16* gp[8];
    u16* lp[8];
#pragma unroll
    for (int j = 0; j < 8; j++) {
        int cid = tid + j * 512;
        int r = cid >> 3, c = cid & 7;
        lp[j] = S + (size_t)cid * 8;            // linear LDS dest (slot 0)
        gp[j] = (r < 256 ? A + (size_t)(m0 + r) * K
                         : WT + (size_t)(n0 + r - 256) * K) + ((c ^ (r & 7)) * 8);
    }

    float4v acc[8][4];
#pragma unroll
    for (int i = 0; i < 8; i++)
#pragma unroll
        for (int j = 0; j < 4; j++) acc[i][j] = (float4v)(0.0f);

    // prologue: stage K-tile 0 into slot 0
#pragma unroll
    for (int j = 0; j < 8; j++) gl_lds16(gp[j], lp[j]);
    __syncthreads();   // vmcnt(0) drain: slot 0 ready

    const int NK = K / 64;   // 16
#pragma unroll 1
    for (int kt = 0; kt < NK; kt++) {
        // issue next tile's stage into the other slot (its readers finished
        // at the previous barrier)
        if (kt + 1 < NK) {
            int so = ((kt + 1) & 1) * 32768;
#pragma unroll
            for (int j = 0; j < 8; j++)
                gl_lds16(gp[j] + (kt + 1) * 64, lp[j] + so);
        }

        const u16* Sb = S + (kt & 1) * 32768;
#pragma unroll
        for (int ks = 0; ks < 2; ks++) {
            int cq = ((ks * 4 + quad) ^ swz) * 8;
            short8 a[8], b[4];
#pragma unroll
            for (int mt = 0; mt < 8; mt++)
                a[mt] = *(const short8*)&Sb[(wm + mt * 16 + l16) * 64 + cq];
#pragma unroll
            for (int nt = 0; nt < 4; nt++)
                b[nt] = *(const short8*)&Sb[(256 + wn + nt * 16 + l16) * 64 + cq];
#pragma unroll
            for (int mt = 0; mt < 8; mt++)
#pragma unroll
                for (int nt = 0; nt < 4; nt++)
                    acc[mt][nt] = __builtin_amdgcn_mfma_f32_16x16x32_bf16(
                        a[mt], b[nt], acc[mt][nt], 0, 0, 0);
        }
        __syncthreads();   // drains this tile's reads + next tile's stage
    }

    // epilogue: QKV layout (Q,K row-major per head; V transposed)
#pragma unroll
    for (int mt = 0; mt < 8; mt++) {
#pragma unroll
        for (int nt = 0; nt < 4; nt++) {
#pragma unroll
            for (int r = 0; r < 4; r++) {
                int m = m0 + wm + mt * 16 + quad * 4 + r;
                int n = n0 + wn + nt * 16 + l16;
                float v = acc[mt][nt][r];
                int bb = m >> 11, t = m & 2047;
                int h = n >> 6, dh = n & 63;
                size_t idx;
                if (z == 2)   // V stored transposed: (b,h,dh,t)
                    idx = (((size_t)2 * BB * HH + bb * HH + h) * DHD + dh) * TT + t;
                else
                    idx = (((size_t)z * BB * HH + bb * HH + h) * TT + t) * DHD + dh;
                outp[idx] = f2bf(v);
            }
        }
    }
}

// ---------------- GEMM (128^2-class, m97 structure): used for the output proj ----------------
template <int MODE, int TM, int TN, int BK>
__global__ __launch_bounds__(256) void gemm_k(const u16* __restrict__ A,
                                              const u16* __restrict__ WT0,
                                              void* __restrict__ outp) {
    const int K = DD;
    const int MT = TM / 32, NT = TN / 32;
    const int NS = (TM + TN) * (BK / 8) / 256;
    const int CPR = BK / 8;

    int z = blockIdx.z;
    const u16* WT = WT0 + (size_t)z * DD * DD;
    int n0 = blockIdx.x * TN, m0 = blockIdx.y * TM;

    __shared__ u16 S[(TM + TN) * BK];

    int tid = threadIdx.x;
    int lane = tid & 63, w = tid >> 6;
    int wm = (w >> 1) * (TM / 2), wn = (w & 1) * (TN / 2);
    int quad = lane >> 4, l16 = lane & 15;

    const u16* gp[NS];
    u16* lp[NS];
#pragma unroll
    for (int j = 0; j < NS; j++) {
        int cid = tid + j * 256;
        int r = cid / CPR, c = cid % CPR;
        lp[j] = S + (size_t)cid * 8;                      // linear LDS dest
        gp[j] = (r < TM ? A + (size_t)(m0 + r) * K
                        : WT + (size_t)(n0 + r - TM) * K) + ((c ^ (r & 7)) * 8);
    }
    int swz = l16 & 7;

    float4v acc[MT][NT];
#pragma unroll
    for (int i = 0; i < MT; i++)
#pragma unroll
        for (int j = 0; j < NT; j++) acc[i][j] = (float4v)(0.0f);

    const int NK = K / BK;
#pragma unroll 1
    for (int ki = 0; ki < NK; ki++) {
        __syncthreads();    // prev compute's S reads done
#pragma unroll
        for (int j = 0; j < NS; j++)
            gl_lds16(gp[j] + ki * BK, lp[j]);
        __syncthreads();    // barrier drain (vmcnt 0) publishes S

#pragma unroll
        for (int ks = 0; ks < BK / 32; ks++) {
            int cq = ((ks * 4 + quad) ^ swz) * 8;
            short8 a[MT], b[NT];
#pragma unroll
            for (int mt = 0; mt < MT; mt++)
                a[mt] = *(const short8*)&S[(wm + mt * 16 + l16) * BK + cq];
#pragma unroll
            for (int nt = 0; nt < NT; nt++)
                b[nt] = *(const short8*)&S[(TM + wn + nt * 16 + l16) * BK + cq];
#pragma unroll
            for (int mt = 0; mt < MT; mt++)
#pragma unroll
                for (int nt = 0; nt < NT; nt++)
                    acc[mt][nt] = __builtin_amdgcn_mfma_f32_16x16x32_bf16(
                        a[mt], b[nt], acc[mt][nt], 0, 0, 0);
        }
    }

#pragma unroll
    for (int mt = 0; mt < MT; mt++) {
#pragma unroll
        for (int nt = 0; nt < NT; nt++) {
#pragma unroll
            for (int r = 0; r < 4; r++) {
                int m = m0 + wm + mt * 16 + quad * 4 + r;
                int n = n0 + wn + nt * 16 + l16;
                float v = acc[mt][nt][r];
                if constexpr (MODE == 0) {
                    int bb = m >> 11, t = m & 2047;
                    int h = n >> 6, dh = n & 63;
                    size_t idx;
                    if (z == 2)
                        idx = (((size_t)2 * BB * HH + bb * HH + h) * DHD + dh) * TT + t;
                    else
                        idx = (((size_t)z * BB * HH + bb * HH + h) * TT + t) * DHD + dh;
                    ((u16*)outp)[idx] = f2bf(v);
                } else {
                    ((float*)outp)[(size_t)m * DD + n] = v;
                }
            }
        }
    }
}

// ---------------- flash attention: split-KV, one block per (bh, q-tile) ----------------
// Verified R2 kernel, verbatim. Both 4-wave groups compute the SAME q-tile;
// group g owns kv tiles 2j+g. No-max softmax => O and rowsum partials combine
// linearly: group 1 dumps partials to LDS once at the end, group 0 adds and
// writes AO. XOR-swizzled unpadded LDS (0-conflict family), S^T trick, exp2.
__global__ __launch_bounds__(512) void attn_k(const u16* __restrict__ QKV,
                                              u16* __restrict__ AO) {
    const u16* Q  = QKV;
    const u16* Kp = QKV + (size_t)MM * DD;
    const u16* Vp = QKV + (size_t)2 * MM * DD;   // V^T: per head [DHD][TT]
    int bh = blockIdx.x;
    int qt = 31 - blockIdx.y;
    size_t hoff = (size_t)bh * TT * DHD;

    __shared__ u16 Ks[2][2][64 * 64];    // [dbuf][group-tile]
    __shared__ u16 VTs[2][2][64 * 64];
    __shared__ u16 Ps[8][16 * 64];       // per-wave P scratch; Q staged in Ps[0..3]

    int tid = threadIdx.x;
    int lane = tid & 63, wv = tid >> 6;      // 8 waves
    int g = wv >> 2, w4 = wv & 3;            // KV-split group, 16-row q block
    int quad = lane >> 4, l16 = lane & 15;
    int cxs = l16 & 7;

    // staging: one 16B chunk per thread per 64x64 tile
    int sr = tid >> 3, sc = tid & 7;
    int sl = sr * 64 + ((sc ^ (sr & 7)) * 8);
    const u16* gK = Kp + hoff + (size_t)sr * DHD + sc * 8;
    const u16* gV = Vp + hoff + (size_t)sr * TT + sc * 8;

    u16* Qstage = &Ps[0][0];   // 8 KB

    // stage Q tile qt, scaled by (1/sqrt(DH)) * log2(e)
    const float qscale = 0.125f * 1.4426950408889634f;
    int q0 = qt * 64;
    {
        short8 v = *(const short8*)(Q + hoff + (size_t)(q0 + sr) * DHD + sc * 8);
        short8 sv;
#pragma unroll
        for (int e = 0; e < 8; e++) sv[e] = (short)f2bf(bf2f((u16)v[e]) * qscale);
        *(short8*)&Qstage[sl] = sv;
    }

    // prefetch round-0 KV tiles (0 and 1)
    short8 prK[2], prV[2];
    prK[0] = *(const short8*)gK;
    prK[1] = *(const short8*)(gK + (size_t)64 * DHD);
    prV[0] = *(const short8*)gV;
    prV[1] = *(const short8*)(gV + 64);

    __syncthreads();   // Q staged
    int fr = w4 * 16 + l16;   // my q-row (local)
    short8 aq0 = *(const short8*)&Qstage[fr * 64 + ((quad ^ cxs) * 8)];
    short8 aq1 = *(const short8*)&Qstage[fr * 64 + (((4 + quad) ^ cxs) * 8)];

    int NR = (qt >> 1) + 1;   // rounds (2 tiles staged per round)

    float4v o[4];
#pragma unroll
    for (int i = 0; i < 4; i++) o[i] = (float4v)(0.0f);
    float lr = 0.0f;

#pragma unroll 1
    for (int jt = 0; jt < NR; jt++) {
        int db = jt & 1;
#pragma unroll
        for (int tt = 0; tt < 2; tt++) {
            *(short8*)&Ks[db][tt][sl]  = prK[tt];
            *(short8*)&VTs[db][tt][sl] = prV[tt];
        }
        __syncthreads();   // publishes round db; drains Q frag reads on jt==0

        if (jt + 1 < NR) {   // prefetch next round's two tiles
            size_t nj = (size_t)(jt + 1) * 128;
            prK[0] = *(const short8*)(gK + nj * DHD);
            prK[1] = *(const short8*)(gK + (nj + 64) * DHD);
            prV[0] = *(const short8*)(gV + nj);
            prV[1] = *(const short8*)(gV + nj + 64);
        }

        int tj = 2 * jt + g;   // my group's tile this round
        if (tj <= qt) {
            // S^T (64 kv x 16 q per wave) = K·Q^T
            float4v s[4];
#pragma unroll
            for (int ct = 0; ct < 4; ct++) {
                int kr = (ct * 16 + l16) * 64;
                short8 ak0 = *(const short8*)&Ks[db][g][kr + ((quad ^ cxs) * 8)];
                short8 ak1 = *(const short8*)&Ks[db][g][kr + (((4 + quad) ^ cxs) * 8)];
                float4v sv = (float4v)(0.0f);
                sv = __builtin_amdgcn_mfma_f32_16x16x32_bf16(ak0, aq0, sv, 0, 0, 0);
                sv = __builtin_amdgcn_mfma_f32_16x16x32_bf16(ak1, aq1, sv, 0, 0, 0);
                s[ct] = sv;   // lane: kv = ct*16+quad*4+r, q = fr
            }

            if (tj == qt) {   // diagonal tile: mask kv > q (local coords)
                int ql = w4 * 16 + l16;
#pragma unroll
                for (int ct = 0; ct < 4; ct++)
#pragma unroll
                    for (int r = 0; r < 4; r++) {
                        int kvl = ct * 16 + quad * 4 + r;
                        if (kvl > ql) s[ct][r] = -30000.0f;
                    }
            }

            // p = v_exp_f32(s); P write (C->A layout) swizzled 8B stores
#pragma unroll
            for (int ct = 0; ct < 4; ct++) {
                float p0 = __builtin_amdgcn_exp2f(s[ct][0]);
                float p1 = __builtin_amdgcn_exp2f(s[ct][1]);
                float p2 = __builtin_amdgcn_exp2f(s[ct][2]);
                float p3 = __builtin_amdgcn_exp2f(s[ct][3]);
                lr += (p0 + p1) + (p2 + p3);
                union { float f; unsigned u; } c0, c1, c2, c3;
                c0.f = p0; c1.f = p1; c2.f = p2; c3.f = p3;
                ushort4 pw;
                pw.x = (u16)(c0.u >> 16);
                pw.y = (u16)(c1.u >> 16);
                pw.z = (u16)(c2.u >> 16);
                pw.w = (u16)(c3.u >> 16);
                int chnk = (ct * 2 + (quad >> 1)) ^ cxs;
                *(ushort4*)&Ps[wv][l16 * 64 + chnk * 8 + (quad & 1) * 4] = pw;
            }

            short8 ap0 = *(const short8*)&Ps[wv][l16 * 64 + ((quad ^ cxs) * 8)];
            short8 ap1 = *(const short8*)&Ps[wv][l16 * 64 + (((4 + quad) ^ cxs) * 8)];
#pragma unroll
            for (int ct = 0; ct < 4; ct++) {
                int vr = (ct * 16 + l16) * 64;
                short8 bv0 = *(const short8*)&VTs[db][g][vr + ((quad ^ cxs) * 8)];
                short8 bv1 = *(const short8*)&VTs[db][g][vr + (((4 + quad) ^ cxs) * 8)];
                o[ct] = __builtin_amdgcn_mfma_f32_16x16x32_bf16(ap0, bv0, o[ct], 0, 0, 0);
                o[ct] = __builtin_amdgcn_mfma_f32_16x16x32_bf16(ap1, bv1, o[ct], 0, 0, 0);
            }
        }
    }

    // combine group partials: group 1 -> LDS, group 0 adds (sums are linear)
    __syncthreads();   // last round's Ks/VTs reads complete before reuse
    float* Of = (float*)&Ks[0][0][0];    // [w4][ct][r][lane] = 16 KB
    float* Lf = (float*)&VTs[0][0][0];   // [w4][lane] = 1 KB
    if (g == 1) {
#pragma unroll
        for (int ct = 0; ct < 4; ct++)
#pragma unroll
            for (int r = 0; r < 4; r++)
                Of[(((w4 * 4 + ct) * 4 + r) * 64) + lane] = o[ct][r];
        Lf[w4 * 64 + lane] = lr;
    }
    __syncthreads();
    if (g == 0) {
#pragma unroll
        for (int ct = 0; ct < 4; ct++)
#pragma unroll
            for (int r = 0; r < 4; r++)
                o[ct][r] += Of[(((w4 * 4 + ct) * 4 + r) * 64) + lane];
        lr += Lf[w4 * 64 + lane];

        // reduce row sums across quads (lane holds q = w4*16 + l16)
        float rs = lr;
        rs += __shfl_xor(rs, 16);
        rs += __shfl_xor(rs, 32);
        int gbase = lane & 48;
        float rinv[4];
#pragma unroll
        for (int r = 0; r < 4; r++)
            rinv[r] = 1.0f / __shfl(rs, gbase + quad * 4 + r);

        int b = bh >> 4, h = bh & 15;
#pragma unroll
        for (int ct = 0; ct < 4; ct++) {
#pragma unroll
            for (int r = 0; r < 4; r++) {
                int q = q0 + w4 * 16 + quad * 4 + r;
                int d = h * 64 + ct * 16 + l16;
                AO[(size_t)(b * TT + q) * DD + d] = f2bf(o[ct][r] * rinv[r]);
            }
        }
    }
}

extern "C" void kernel_launch(void* const* d_in, const int* in_sizes, int n_in,
                              void* d_out, int out_size, void* d_ws, size_t ws_size,
                              hipStream_t stream) {
    const float* x  = (const float*)d_in[0];
    const float* Wq = (const float*)d_in[1];
    const float* Wk = (const float*)d_in[2];
    const float* Wv = (const float*)d_in[3];
    const float* Wo = (const float*)d_in[4];

    u16* xb  = (u16*)d_ws;                       // 8 MB  : x in bf16
    u16* WT  = xb + (size_t)MM * DD;             // 8 MB  : 4 transposed weights bf16
    u16* QKV = WT + (size_t)4 * DD * DD;         // 24 MB : Q,K (b,h,t,dh) + V^T (b,h,dh,t)
    u16* AO  = QKV + (size_t)3 * MM * DD;        // 8 MB  : attention out (B,T,D) bf16
    float* out = (float*)d_out;

    prep_k<<<dim3(32, 32, 5), 256, 0, stream>>>(x, Wq, Wk, Wv, Wo, xb, WT);
    gemmq_k<<<dim3(DD / 256, MM / 256, 3), 512, 0, stream>>>(xb, WT, QKV);
    attn_k<<<dim3(32, 32), 512, 0, stream>>>(QKV, AO);
    gemm_k<1, 64, 128, 64><<<dim3(DD / 128, MM / 64, 1), 256, 0, stream>>>(AO, WT + (size_t)3 * DD * DD, out);
}

// Round 10
// 176.164 us; speedup vs baseline: 1.3007x; 1.0708x over previous
//
#include <hip/hip_runtime.h>

#define BB 2
#define TT 2048
#define DD 1024
#define HH 16
#define DHD 64
#define MM (BB*TT)   // 4096

typedef __attribute__((ext_vector_type(8))) short short8;
typedef __attribute__((ext_vector_type(4))) float float4v;
typedef unsigned short u16;

__device__ inline float bf2f(u16 u) {
    union { unsigned int i; float f; } v;
    v.i = ((unsigned int)u) << 16;
    return v.f;
}
__device__ inline u16 f2bf(float f) {
    union { float f; unsigned int i; } v;
    v.f = f;
    unsigned int x = v.i;
    unsigned int r = (x + 0x7fffu + ((x >> 16) & 1u)) >> 16;
    return (u16)r;
}

// async 16B global->LDS (DMA, no VGPR round-trip)
__device__ inline void gl_lds16(const u16* g, u16* l) {
    __builtin_amdgcn_global_load_lds(
        (const __attribute__((address_space(1))) unsigned int*)g,
        (__attribute__((address_space(3))) unsigned int*)l, 16, 0, 0);
}

// counted vmcnt wait (immediates must be literals)
template <int N> __device__ inline void wait_vmcnt() {
    if constexpr (N == 0) asm volatile("s_waitcnt vmcnt(0)" ::: "memory");
    else if constexpr (N == 3) asm volatile("s_waitcnt vmcnt(3)" ::: "memory");
    else if constexpr (N == 4) asm volatile("s_waitcnt vmcnt(4)" ::: "memory");
    else if constexpr (N == 6) asm volatile("s_waitcnt vmcnt(6)" ::: "memory");
    else if constexpr (N == 8) asm volatile("s_waitcnt vmcnt(8)" ::: "memory");
}

// ---------------- prep: fused x-cast (z==4) + weight cast/transpose (z<4) ----------------
__global__ __launch_bounds__(256) void prep_k(const float* __restrict__ x,
                                              const float* __restrict__ Wq,
                                              const float* __restrict__ Wk,
                                              const float* __restrict__ Wv,
                                              const float* __restrict__ Wo,
                                              u16* __restrict__ xb,
                                              u16* __restrict__ WT) {
    int tid = threadIdx.x;
    if (blockIdx.z == 4) {   // cast x: 1024 blocks x 1024 float4
        int bid = blockIdx.y * 32 + blockIdx.x;
#pragma unroll
        for (int k = 0; k < 4; k++) {
            int i = bid * 1024 + k * 256 + tid;
            float4v v = ((const float4v*)x)[i];
            ushort4 o;
            o.x = f2bf(v[0]); o.y = f2bf(v[1]); o.z = f2bf(v[2]); o.w = f2bf(v[3]);
            ((ushort4*)xb)[i] = o;
        }
        return;
    }
    __shared__ u16 t[32][33];
    int wsel = blockIdx.z;
    const float* W = (wsel == 0) ? Wq : (wsel == 1) ? Wk : (wsel == 2) ? Wv : Wo;
    u16* o = WT + (size_t)wsel * DD * DD;
    int k0 = blockIdx.y * 32, n0 = blockIdx.x * 32;
    int tx = tid & 31, ty = tid >> 5;   // 32 x 8
#pragma unroll
    for (int i = 0; i < 4; i++) {
        int k = ty + i * 8;
        t[k][tx] = f2bf(W[(size_t)(k0 + k) * DD + n0 + tx]);
    }
    __syncthreads();
    // vectorized write-back: lane = (row n, 4-wide k chunk) -> ushort4 store
    int n = tid >> 3, kc = tid & 7;
    ushort4 w4v;
    w4v.x = t[kc * 4 + 0][n];
    w4v.y = t[kc * 4 + 1][n];
    w4v.z = t[kc * 4 + 2][n];
    w4v.w = t[kc * 4 + 3][n];
    *(ushort4*)&o[(size_t)(n0 + n) * DD + k0 + kc * 4] = w4v;
}

// ---------------- GEMM v2: BK=32, 3-slot rotation, counted vmcnt, raw barriers ----------------
// T4 mechanism (m201/m218-verified): ONE raw s_barrier per K-tile preceded by
// s_waitcnt vmcnt(CH) -- completes only the tile about to be computed; the
// next stage's CH loads stay in flight ACROSS the barrier (no vmcnt(0) drain).
// Race safety (3 slots, stage 2 tiles ahead):
//   interval (B_kt, B_{kt+1}) contains: issue stage(kt+3) + compute(kt+1).
//   - stage(kt+3) writes slot (kt+3)%3 == kt%3: its readers, compute(kt),
//     finished before B_kt (ds_reads consumed by MFMAs emitted before the
//     barrier; lgkmcnt dependency forces completion pre-arrival).
//   - in-flight stage(kt+2) writes (kt+2)%3 != (kt+1)%3 (compute's slot).
//   Robust even if the compiler hoists a stage one interval up (slot
//   distance stays >= 1 from any concurrent reader).
// Swizzle family re-derived for 4-chunk rows: store src chunk (c^(r&3)),
// read chunk (quad^(l16&3)) -- same involution pair as the verified BK=64;
// bank enumeration: exactly 8 dword-accesses/bank (balanced, conflict-free).
// sched_barrier(0) after each barrier pins ds_reads below it (rule #18).
template <int MODE, int TM, int TN>
__global__ __launch_bounds__(256) void gemm_k2(const u16* __restrict__ A,
                                               const u16* __restrict__ WT0,
                                               void* __restrict__ outp) {
    const int BK = 32;
    const int K = DD;
    const int NK = K / BK;                 // 32
    const int MT = TM / 32, NT = TN / 32;  // per-wave fragment repeats (2x2 waves)
    const int ROWS = TM + TN;
    const int CH = ROWS / 64;              // gl_lds per thread per stage
    const int SLOT = ROWS * BK;            // u16s per slot

    int z = blockIdx.z;
    const u16* WT = WT0 + (size_t)z * DD * DD;
    int n0 = blockIdx.x * TN, m0 = blockIdx.y * TM;

    __shared__ u16 S[3 * SLOT];

    int tid = threadIdx.x;
    int lane = tid & 63, w = tid >> 6;
    int wm = (w >> 1) * (TM / 2), wn = (w & 1) * (TN / 2);
    int quad = lane >> 4, l16 = lane & 15;
    int swz = l16 & 3;

    const u16* gp[CH];
    u16* lp[CH];
#pragma unroll
    for (int j = 0; j < CH; j++) {
        int cid = tid + j * 256;
        int r = cid >> 2, c = cid & 3;
        lp[j] = S + (size_t)cid * 8;       // linear LDS dest (slot 0)
        gp[j] = (r < TM ? A + (size_t)(m0 + r) * K
                        : WT + (size_t)(n0 + r - TM) * K) + ((c ^ (r & 3)) * 8);
    }

    float4v acc[MT][NT];
#pragma unroll
    for (int i = 0; i < MT; i++)
#pragma unroll
        for (int j = 0; j < NT; j++) acc[i][j] = (float4v)(0.0f);

    // prologue: stage tiles 0 and 1; wait for 0 (1 stays in flight)
#pragma unroll
    for (int j = 0; j < CH; j++) gl_lds16(gp[j], lp[j]);
#pragma unroll
    for (int j = 0; j < CH; j++) gl_lds16(gp[j] + BK, lp[j] + SLOT);
    wait_vmcnt<CH>();
    __builtin_amdgcn_s_barrier();
    __builtin_amdgcn_sched_barrier(0);

#pragma unroll 1
    for (int kt = 0; kt < NK; kt++) {
        if (kt + 2 < NK) {                 // stage kt+2 into slot (kt+2)%3
            int so = ((kt + 2) % 3) * SLOT;
            int go = (kt + 2) * BK;
#pragma unroll
            for (int j = 0; j < CH; j++) gl_lds16(gp[j] + go, lp[j] + so);
        }

        const u16* Sb = S + (kt % 3) * SLOT;
        int cq = (quad ^ swz) * 8;
        short8 a[MT], b[NT];
#pragma unroll
        for (int mt = 0; mt < MT; mt++)
            a[mt] = *(const short8*)&Sb[(wm + mt * 16 + l16) * BK + cq];
#pragma unroll
        for (int nt = 0; nt < NT; nt++)
            b[nt] = *(const short8*)&Sb[(TM + wn + nt * 16 + l16) * BK + cq];
#pragma unroll
        for (int mt = 0; mt < MT; mt++)
#pragma unroll
            for (int nt = 0; nt < NT; nt++)
                acc[mt][nt] = __builtin_amdgcn_mfma_f32_16x16x32_bf16(
                    a[mt], b[nt], acc[mt][nt], 0, 0, 0);

        if (kt + 1 < NK) {                 // gate compute(kt+1): finish stage(kt+1)
            if (kt + 2 < NK) wait_vmcnt<CH>(); else wait_vmcnt<0>();
            __builtin_amdgcn_s_barrier();
            __builtin_amdgcn_sched_barrier(0);
        }
    }

#pragma unroll
    for (int mt = 0; mt < MT; mt++) {
#pragma unroll
        for (int nt = 0; nt < NT; nt++) {
#pragma unroll
            for (int r = 0; r < 4; r++) {
                int m = m0 + wm + mt * 16 + quad * 4 + r;
                int n = n0 + wn + nt * 16 + l16;
                float v = acc[mt][nt][r];
                if constexpr (MODE == 0) {
                    int bb = m >> 11, t = m & 2047;
                    int h = n >> 6, dh = n & 63;
                    size_t idx;
                    if (z == 2)   // V stored transposed: (b,h,dh,t)
                        idx = (((size_t)2 * BB * HH + bb * HH + h) * DHD + dh) * TT + t;
                    else
                        idx = (((size_t)z * BB * HH + bb * HH + h) * TT + t) * DHD + dh;
                    ((u16*)outp)[idx] = f2bf(v);
                } else {
                    ((float*)outp)[(size_t)m * DD + n] = v;
                }
            }
        }
    }
}

// ---------------- flash attention: split-KV, one block per (bh, q-tile) ----------------
// Verified R2 kernel, verbatim (40.9us). Both 4-wave groups compute the SAME
// q-tile; group g owns kv tiles 2j+g. No-max softmax => partials combine
// linearly at the end. XOR-swizzled unpadded LDS, S^T trick, exp2 domain.
__global__ __launch_bounds__(512) void attn_k(const u16* __restrict__ QKV,
                                              u16* __restrict__ AO) {
    const u16* Q  = QKV;
    const u16* Kp = QKV + (size_t)MM * DD;
    const u16* Vp = QKV + (size_t)2 * MM * DD;   // V^T: per head [DHD][TT]
    int bh = blockIdx.x;
    int qt = 31 - blockIdx.y;
    size_t hoff = (size_t)bh * TT * DHD;

    __shared__ u16 Ks[2][2][64 * 64];    // [dbuf][group-tile]
    __shared__ u16 VTs[2][2][64 * 64];
    __shared__ u16 Ps[8][16 * 64];       // per-wave P scratch; Q staged in Ps[0..3]

    int tid = threadIdx.x;
    int lane = tid & 63, wv = tid >> 6;      // 8 waves
    int g = wv >> 2, w4 = wv & 3;            // KV-split group, 16-row q block
    int quad = lane >> 4, l16 = lane & 15;
    int cxs = l16 & 7;

    // staging: one 16B chunk per thread per 64x64 tile
    int sr = tid >> 3, sc = tid & 7;
    int sl = sr * 64 + ((sc ^ (sr & 7)) * 8);
    const u16* gK = Kp + hoff + (size_t)sr * DHD + sc * 8;
    const u16* gV = Vp + hoff + (size_t)sr * TT + sc * 8;

    u16* Qstage = &Ps[0][0];   // 8 KB

    // stage Q tile qt, scaled by (1/sqrt(DH)) * log2(e)
    const float qscale = 0.125f * 1.4426950408889634f;
    int q0 = qt * 64;
    {
        short8 v = *(const short8*)(Q + hoff + (size_t)(q0 + sr) * DHD + sc * 8);
        short8 sv;
#pragma unroll
        for (int e = 0; e < 8; e++) sv[e] = (short)f2bf(bf2f((u16)v[e]) * qscale);
        *(short8*)&Qstage[sl] = sv;
    }

    // prefetch round-0 KV tiles (0 and 1)
    short8 prK[2], prV[2];
    prK[0] = *(const short8*)gK;
    prK[1] = *(const short8*)(gK + (size_t)64 * DHD);
    prV[0] = *(const short8*)gV;
    prV[1] = *(const short8*)(gV + 64);

    __syncthreads();   // Q staged
    int fr = w4 * 16 + l16;   // my q-row (local)
    short8 aq0 = *(const short8*)&Qstage[fr * 64 + ((quad ^ cxs) * 8)];
    short8 aq1 = *(const short8*)&Qstage[fr * 64 + (((4 + quad) ^ cxs) * 8)];

    int NR = (qt >> 1) + 1;   // rounds (2 tiles staged per round)

    float4v o[4];
#pragma unroll
    for (int i = 0; i < 4; i++) o[i] = (float4v)(0.0f);
    float lr = 0.0f;

#pragma unroll 1
    for (int jt = 0; jt < NR; jt++) {
        int db = jt & 1;
#pragma unroll
        for (int tt = 0; tt < 2; tt++) {
            *(short8*)&Ks[db][tt][sl]  = prK[tt];
            *(short8*)&VTs[db][tt][sl] = prV[tt];
        }
        __syncthreads();   // publishes round db; drains Q frag reads on jt==0

        if (jt + 1 < NR) {   // prefetch next round's two tiles
            size_t nj = (size_t)(jt + 1) * 128;
            prK[0] = *(const short8*)(gK + nj * DHD);
            prK[1] = *(const short8*)(gK + (nj + 64) * DHD);
            prV[0] = *(const short8*)(gV + nj);
            prV[1] = *(const short8*)(gV + nj + 64);
        }

        int tj = 2 * jt + g;   // my group's tile this round
        if (tj <= qt) {
            // S^T (64 kv x 16 q per wave) = K·Q^T
            float4v s[4];
#pragma unroll
            for (int ct = 0; ct < 4; ct++) {
                int kr = (ct * 16 + l16) * 64;
                short8 ak0 = *(const short8*)&Ks[db][g][kr + ((quad ^ cxs) * 8)];
                short8 ak1 = *(const short8*)&Ks[db][g][kr + (((4 + quad) ^ cxs) * 8)];
                float4v sv = (float4v)(0.0f);
                sv = __builtin_amdgcn_mfma_f32_16x16x32_bf16(ak0, aq0, sv, 0, 0, 0);
                sv = __builtin_amdgcn_mfma_f32_16x16x32_bf16(ak1, aq1, sv, 0, 0, 0);
                s[ct] = sv;   // lane: kv = ct*16+quad*4+r, q = fr
            }

            if (tj == qt) {   // diagonal tile: mask kv > q (local coords)
                int ql = w4 * 16 + l16;
#pragma unroll
                for (int ct = 0; ct < 4; ct++)
#pragma unroll
                    for (int r = 0; r < 4; r++) {
                        int kvl = ct * 16 + quad * 4 + r;
                        if (kvl > ql) s[ct][r] = -30000.0f;
                    }
            }

            // p = v_exp_f32(s); P write (C->A layout) swizzled 8B stores
#pragma unroll
            for (int ct = 0; ct < 4; ct++) {
                float p0 = __builtin_amdgcn_exp2f(s[ct][0]);
                float p1 = __builtin_amdgcn_exp2f(s[ct][1]);
                float p2 = __builtin_amdgcn_exp2f(s[ct][2]);
                float p3 = __builtin_amdgcn_exp2f(s[ct][3]);
                lr += (p0 + p1) + (p2 + p3);
                union { float f; unsigned u; } c0, c1, c2, c3;
                c0.f = p0; c1.f = p1; c2.f = p2; c3.f = p3;
                ushort4 pw;
                pw.x = (u16)(c0.u >> 16);
                pw.y = (u16)(c1.u >> 16);
                pw.z = (u16)(c2.u >> 16);
                pw.w = (u16)(c3.u >> 16);
                int chnk = (ct * 2 + (quad >> 1)) ^ cxs;
                *(ushort4*)&Ps[wv][l16 * 64 + chnk * 8 + (quad & 1) * 4] = pw;
            }

            short8 ap0 = *(const short8*)&Ps[wv][l16 * 64 + ((quad ^ cxs) * 8)];
            short8 ap1 = *(const short8*)&Ps[wv][l16 * 64 + (((4 + quad) ^ cxs) * 8)];
#pragma unroll
            for (int ct = 0; ct < 4; ct++) {
                int vr = (ct * 16 + l16) * 64;
                short8 bv0 = *(const short8*)&VTs[db][g][vr + ((quad ^ cxs) * 8)];
                short8 bv1 = *(const short8*)&VTs[db][g][vr + (((4 + quad) ^ cxs) * 8)];
                o[ct] = __builtin_amdgcn_mfma_f32_16x16x32_bf16(ap0, bv0, o[ct], 0, 0, 0);
                o[ct] = __builtin_amdgcn_mfma_f32_16x16x32_bf16(ap1, bv1, o[ct], 0, 0, 0);
            }
        }
    }

    // combine group partials: group 1 -> LDS, group 0 adds (sums are linear)
    __syncthreads();   // last round's Ks/VTs reads complete before reuse
    float* Of = (float*)&Ks[0][0][0];    // [w4][ct][r][lane] = 16 KB
    float* Lf = (float*)&VTs[0][0][0];   // [w4][lane] = 1 KB
    if (g == 1) {
#pragma unroll
        for (int ct = 0; ct < 4; ct++)
#pragma unroll
            for (int r = 0; r < 4; r++)
                Of[(((w4 * 4 + ct) * 4 + r) * 64) + lane] = o[ct][r];
        Lf[w4 * 64 + lane] = lr;
    }
    __syncthreads();
    if (g == 0) {
#pragma unroll
        for (int ct = 0; ct < 4; ct++)
#pragma unroll
            for (int r = 0; r < 4; r++)
                o[ct][r] += Of[(((w4 * 4 + ct) * 4 + r) * 64) + lane];
        lr += Lf[w4 * 64 + lane];

        // reduce row sums across quads (lane holds q = w4*16 + l16)
        float rs = lr;
        rs += __shfl_xor(rs, 16);
        rs += __shfl_xor(rs, 32);
        int gbase = lane & 48;
        float rinv[4];
#pragma unroll
        for (int r = 0; r < 4; r++)
            rinv[r] = 1.0f / __shfl(rs, gbase + quad * 4 + r);

        int b = bh >> 4, h = bh & 15;
#pragma unroll
        for (int ct = 0; ct < 4; ct++) {
#pragma unroll
            for (int r = 0; r < 4; r++) {
                int q = q0 + w4 * 16 + quad * 4 + r;
                int d = h * 64 + ct * 16 + l16;
                AO[(size_t)(b * TT + q) * DD + d] = f2bf(o[ct][r] * rinv[r]);
            }
        }
    }
}

extern "C" void kernel_launch(void* const* d_in, const int* in_sizes, int n_in,
                              void* d_out, int out_size, void* d_ws, size_t ws_size,
                              hipStream_t stream) {
    const float* x  = (const float*)d_in[0];
    const float* Wq = (const float*)d_in[1];
    const float* Wk = (const float*)d_in[2];
    const float* Wv = (const float*)d_in[3];
    const float* Wo = (const float*)d_in[4];

    u16* xb  = (u16*)d_ws;                       // 8 MB  : x in bf16
    u16* WT  = xb + (size_t)MM * DD;             // 8 MB  : 4 transposed weights bf16
    u16* QKV = WT + (size_t)4 * DD * DD;         // 24 MB : Q,K (b,h,t,dh) + V^T (b,h,dh,t)
    u16* AO  = QKV + (size_t)3 * MM * DD;        // 8 MB  : attention out (B,T,D) bf16
    float* out = (float*)d_out;

    prep_k<<<dim3(32, 32, 5), 256, 0, stream>>>(x, Wq, Wk, Wv, Wo, xb, WT);
    gemm_k2<0, 128, 128><<<dim3(DD / 128, MM / 128, 3), 256, 0, stream>>>(xb, WT, QKV);
    attn_k<<<dim3(32, 32), 512, 0, stream>>>(QKV, AO);
    gemm_k2<1, 64, 128><<<dim3(DD / 128, MM / 64, 1), 256, 0, stream>>>(AO, WT + (size_t)3 * DD * DD, out);
}

// Round 11
// 171.888 us; speedup vs baseline: 1.3331x; 1.0249x over previous
//
#include <hip/hip_runtime.h>

#define BB 2
#define TT 2048
#define DD 1024
#define HH 16
#define DHD 64
#define MM (BB*TT)   // 4096

typedef __attribute__((ext_vector_type(8))) short short8;
typedef __attribute__((ext_vector_type(4))) float float4v;
typedef unsigned short u16;

__device__ inline float bf2f(u16 u) {
    union { unsigned int i; float f; } v;
    v.i = ((unsigned int)u) << 16;
    return v.f;
}
__device__ inline u16 f2bf(float f) {
    union { float f; unsigned int i; } v;
    v.f = f;
    unsigned int x = v.i;
    unsigned int r = (x + 0x7fffu + ((x >> 16) & 1u)) >> 16;
    return (u16)r;
}

// async 16B global->LDS (DMA, no VGPR round-trip)
__device__ inline void gl_lds16(const u16* g, u16* l) {
    __builtin_amdgcn_global_load_lds(
        (const __attribute__((address_space(1))) unsigned int*)g,
        (__attribute__((address_space(3))) unsigned int*)l, 16, 0, 0);
}

// ---------------- prep: fused x-cast (z==4) + weight cast/transpose (z<4) ----------------
__global__ __launch_bounds__(256) void prep_k(const float* __restrict__ x,
                                              const float* __restrict__ Wq,
                                              const float* __restrict__ Wk,
                                              const float* __restrict__ Wv,
                                              const float* __restrict__ Wo,
                                              u16* __restrict__ xb,
                                              u16* __restrict__ WT) {
    int tid = threadIdx.x;
    if (blockIdx.z == 4) {   // cast x: 1024 blocks x 1024 float4
        int bid = blockIdx.y * 32 + blockIdx.x;
#pragma unroll
        for (int k = 0; k < 4; k++) {
            int i = bid * 1024 + k * 256 + tid;
            float4v v = ((const float4v*)x)[i];
            ushort4 o;
            o.x = f2bf(v[0]); o.y = f2bf(v[1]); o.z = f2bf(v[2]); o.w = f2bf(v[3]);
            ((ushort4*)xb)[i] = o;
        }
        return;
    }
    __shared__ u16 t[32][33];
    int wsel = blockIdx.z;
    const float* W = (wsel == 0) ? Wq : (wsel == 1) ? Wk : (wsel == 2) ? Wv : Wo;
    u16* o = WT + (size_t)wsel * DD * DD;
    int k0 = blockIdx.y * 32, n0 = blockIdx.x * 32;
    int tx = tid & 31, ty = tid >> 5;   // 32 x 8
#pragma unroll
    for (int i = 0; i < 4; i++) {
        int k = ty + i * 8;
        t[k][tx] = f2bf(W[(size_t)(k0 + k) * DD + n0 + tx]);
    }
    __syncthreads();
    // vectorized write-back: lane = (row n, 4-wide k chunk) -> ushort4 store
    int n = tid >> 3, kc = tid & 7;
    ushort4 w4v;
    w4v.x = t[kc * 4 + 0][n];
    w4v.y = t[kc * 4 + 1][n];
    w4v.z = t[kc * 4 + 2][n];
    w4v.w = t[kc * 4 + 3][n];
    *(ushort4*)&o[(size_t)(n0 + n) * DD + k0 + kc * 4] = w4v;
}

// ---------------- GEMM v3: BK=64, 2-slot dbuf, catalog minimum-2-phase ----------------
// T3 recipe verbatim: per K-tile { STAGE(kt+1 -> slot^1) issued FIRST;
// compute(kt, slot); vmcnt(0); s_barrier }. The vmcnt(0) is LATE: stage(kt+1)
// had the whole ds_read+MFMA phase (~500cyc) to land, vs the R2 gemm's cold
// drain immediately after issue. Exactly ONE barrier per K-tile.
// Race safety (2 slots, 1 ahead): stage(kt+1) writes slot (kt+1)&1, whose
// readers were compute(kt-1) -- finished before the barrier that ended
// interval kt-1. sched_barrier(0) after each s_barrier blocks hoisting of
// iteration kt+1's stage (targets compute(kt)'s slot!) across the barrier
// (rule #18). BK=64 restores the VERIFIED swizzle family: 128B rows span
// all 32 banks; store chunk (c^(r&7)), read chunk ((ks*4+quad)^(l16&7)) --
// byte-identical to the 0-conflict R2 gemm. Full-line staging restores
// FETCH to ~23MB (BK=32's 64B rows double-fetched every 128B line).
template <int MODE, int TM, int TN>
__global__ __launch_bounds__(256) void gemm_k3(const u16* __restrict__ A,
                                               const u16* __restrict__ WT0,
                                               void* __restrict__ outp) {
    const int BK = 64;
    const int K = DD;
    const int NK = K / BK;                 // 16
    const int MT = TM / 32, NT = TN / 32;
    const int ROWS = TM + TN;
    const int CH = ROWS / 32;              // 16B chunks per thread per stage
    const int SLOT = ROWS * BK;            // u16s per slot

    int z = blockIdx.z;
    const u16* WT = WT0 + (size_t)z * DD * DD;
    int n0 = blockIdx.x * TN, m0 = blockIdx.y * TM;

    __shared__ u16 S[2 * SLOT];

    int tid = threadIdx.x;
    int lane = tid & 63, w = tid >> 6;
    int wm = (w >> 1) * (TM / 2), wn = (w & 1) * (TN / 2);
    int quad = lane >> 4, l16 = lane & 15;
    int swz = l16 & 7;

    const u16* gp[CH];
    u16* lp[CH];
#pragma unroll
    for (int j = 0; j < CH; j++) {
        int cid = tid + j * 256;
        int r = cid >> 3, c = cid & 7;
        lp[j] = S + (size_t)cid * 8;       // linear LDS dest (slot 0)
        gp[j] = (r < TM ? A + (size_t)(m0 + r) * K
                        : WT + (size_t)(n0 + r - TM) * K) + ((c ^ (r & 7)) * 8);
    }

    float4v acc[MT][NT];
#pragma unroll
    for (int i = 0; i < MT; i++)
#pragma unroll
        for (int j = 0; j < NT; j++) acc[i][j] = (float4v)(0.0f);

    // prologue: stage tile 0 into slot 0, drain, barrier
#pragma unroll
    for (int j = 0; j < CH; j++) gl_lds16(gp[j], lp[j]);
    asm volatile("s_waitcnt vmcnt(0)" ::: "memory");
    __builtin_amdgcn_s_barrier();
    __builtin_amdgcn_sched_barrier(0);

#pragma unroll 1
    for (int kt = 0; kt < NK; kt++) {
        if (kt + 1 < NK) {                 // STAGE first (issue-early)
            int so = ((kt + 1) & 1) * SLOT;
            int go = (kt + 1) * BK;
#pragma unroll
            for (int j = 0; j < CH; j++) gl_lds16(gp[j] + go, lp[j] + so);
        }

        const u16* Sb = S + (kt & 1) * SLOT;
#pragma unroll
        for (int ks = 0; ks < 2; ks++) {
            int cq = ((ks * 4 + quad) ^ swz) * 8;
            short8 a[MT], b[NT];
#pragma unroll
            for (int mt = 0; mt < MT; mt++)
                a[mt] = *(const short8*)&Sb[(wm + mt * 16 + l16) * BK + cq];
#pragma unroll
            for (int nt = 0; nt < NT; nt++)
                b[nt] = *(const short8*)&Sb[(TM + wn + nt * 16 + l16) * BK + cq];
#pragma unroll
            for (int mt = 0; mt < MT; mt++)
#pragma unroll
                for (int nt = 0; nt < NT; nt++)
                    acc[mt][nt] = __builtin_amdgcn_mfma_f32_16x16x32_bf16(
                        a[mt], b[nt], acc[mt][nt], 0, 0, 0);
        }

        if (kt + 1 < NK) {                 // wait LATE: stage(kt+1) has landed by now
            asm volatile("s_waitcnt vmcnt(0)" ::: "memory");
            __builtin_amdgcn_s_barrier();
            __builtin_amdgcn_sched_barrier(0);
        }
    }

#pragma unroll
    for (int mt = 0; mt < MT; mt++) {
#pragma unroll
        for (int nt = 0; nt < NT; nt++) {
#pragma unroll
            for (int r = 0; r < 4; r++) {
                int m = m0 + wm + mt * 16 + quad * 4 + r;
                int n = n0 + wn + nt * 16 + l16;
                float v = acc[mt][nt][r];
                if constexpr (MODE == 0) {
                    int bb = m >> 11, t = m & 2047;
                    int h = n >> 6, dh = n & 63;
                    size_t idx;
                    if (z == 2)   // V stored transposed: (b,h,dh,t)
                        idx = (((size_t)2 * BB * HH + bb * HH + h) * DHD + dh) * TT + t;
                    else
                        idx = (((size_t)z * BB * HH + bb * HH + h) * TT + t) * DHD + dh;
                    ((u16*)outp)[idx] = f2bf(v);
                } else {
                    ((float*)outp)[(size_t)m * DD + n] = v;
                }
            }
        }
    }
}

// ---------------- flash attention: split-KV, one block per (bh, q-tile) ----------------
// Verified R2 kernel, verbatim (40.9us). Both 4-wave groups compute the SAME
// q-tile; group g owns kv tiles 2j+g. No-max softmax => partials combine
// linearly at the end. XOR-swizzled unpadded LDS, S^T trick, exp2 domain.
__global__ __launch_bounds__(512) void attn_k(const u16* __restrict__ QKV,
                                              u16* __restrict__ AO) {
    const u16* Q  = QKV;
    const u16* Kp = QKV + (size_t)MM * DD;
    const u16* Vp = QKV + (size_t)2 * MM * DD;   // V^T: per head [DHD][TT]
    int bh = blockIdx.x;
    int qt = 31 - blockIdx.y;
    size_t hoff = (size_t)bh * TT * DHD;

    __shared__ u16 Ks[2][2][64 * 64];    // [dbuf][group-tile]
    __shared__ u16 VTs[2][2][64 * 64];
    __shared__ u16 Ps[8][16 * 64];       // per-wave P scratch; Q staged in Ps[0..3]

    int tid = threadIdx.x;
    int lane = tid & 63, wv = tid >> 6;      // 8 waves
    int g = wv >> 2, w4 = wv & 3;            // KV-split group, 16-row q block
    int quad = lane >> 4, l16 = lane & 15;
    int cxs = l16 & 7;

    // staging: one 16B chunk per thread per 64x64 tile
    int sr = tid >> 3, sc = tid & 7;
    int sl = sr * 64 + ((sc ^ (sr & 7)) * 8);
    const u16* gK = Kp + hoff + (size_t)sr * DHD + sc * 8;
    const u16* gV = Vp + hoff + (size_t)sr * TT + sc * 8;

    u16* Qstage = &Ps[0][0];   // 8 KB

    // stage Q tile qt, scaled by (1/sqrt(DH)) * log2(e)
    const float qscale = 0.125f * 1.4426950408889634f;
    int q0 = qt * 64;
    {
        short8 v = *(const short8*)(Q + hoff + (size_t)(q0 + sr) * DHD + sc * 8);
        short8 sv;
#pragma unroll
        for (int e = 0; e < 8; e++) sv[e] = (short)f2bf(bf2f((u16)v[e]) * qscale);
        *(short8*)&Qstage[sl] = sv;
    }

    // prefetch round-0 KV tiles (0 and 1)
    short8 prK[2], prV[2];
    prK[0] = *(const short8*)gK;
    prK[1] = *(const short8*)(gK + (size_t)64 * DHD);
    prV[0] = *(const short8*)gV;
    prV[1] = *(const short8*)(gV + 64);

    __syncthreads();   // Q staged
    int fr = w4 * 16 + l16;   // my q-row (local)
    short8 aq0 = *(const short8*)&Qstage[fr * 64 + ((quad ^ cxs) * 8)];
    short8 aq1 = *(const short8*)&Qstage[fr * 64 + (((4 + quad) ^ cxs) * 8)];

    int NR = (qt >> 1) + 1;   // rounds (2 tiles staged per round)

    float4v o[4];
#pragma unroll
    for (int i = 0; i < 4; i++) o[i] = (float4v)(0.0f);
    float lr = 0.0f;

#pragma unroll 1
    for (int jt = 0; jt < NR; jt++) {
        int db = jt & 1;
#pragma unroll
        for (int tt = 0; tt < 2; tt++) {
            *(short8*)&Ks[db][tt][sl]  = prK[tt];
            *(short8*)&VTs[db][tt][sl] = prV[tt];
        }
        __syncthreads();   // publishes round db; drains Q frag reads on jt==0

        if (jt + 1 < NR) {   // prefetch next round's two tiles
            size_t nj = (size_t)(jt + 1) * 128;
            prK[0] = *(const short8*)(gK + nj * DHD);
            prK[1] = *(const short8*)(gK + (nj + 64) * DHD);
            prV[0] = *(const short8*)(gV + nj);
            prV[1] = *(const short8*)(gV + nj + 64);
        }

        int tj = 2 * jt + g;   // my group's tile this round
        if (tj <= qt) {
            // S^T (64 kv x 16 q per wave) = K·Q^T
            float4v s[4];
#pragma unroll
            for (int ct = 0; ct < 4; ct++) {
                int kr = (ct * 16 + l16) * 64;
                short8 ak0 = *(const short8*)&Ks[db][g][kr + ((quad ^ cxs) * 8)];
                short8 ak1 = *(const short8*)&Ks[db][g][kr + (((4 + quad) ^ cxs) * 8)];
                float4v sv = (float4v)(0.0f);
                sv = __builtin_amdgcn_mfma_f32_16x16x32_bf16(ak0, aq0, sv, 0, 0, 0);
                sv = __builtin_amdgcn_mfma_f32_16x16x32_bf16(ak1, aq1, sv, 0, 0, 0);
                s[ct] = sv;   // lane: kv = ct*16+quad*4+r, q = fr
            }

            if (tj == qt) {   // diagonal tile: mask kv > q (local coords)
                int ql = w4 * 16 + l16;
#pragma unroll
                for (int ct = 0; ct < 4; ct++)
#pragma unroll
                    for (int r = 0; r < 4; r++) {
                        int kvl = ct * 16 + quad * 4 + r;
                        if (kvl > ql) s[ct][r] = -30000.0f;
                    }
            }

            // p = v_exp_f32(s); P write (C->A layout) swizzled 8B stores
#pragma unroll
            for (int ct = 0; ct < 4; ct++) {
                float p0 = __builtin_amdgcn_exp2f(s[ct][0]);
                float p1 = __builtin_amdgcn_exp2f(s[ct][1]);
                float p2 = __builtin_amdgcn_exp2f(s[ct][2]);
                float p3 = __builtin_amdgcn_exp2f(s[ct][3]);
                lr += (p0 + p1) + (p2 + p3);
                union { float f; unsigned u; } c0, c1, c2, c3;
                c0.f = p0; c1.f = p1; c2.f = p2; c3.f = p3;
                ushort4 pw;
                pw.x = (u16)(c0.u >> 16);
                pw.y = (u16)(c1.u >> 16);
                pw.z = (u16)(c2.u >> 16);
                pw.w = (u16)(c3.u >> 16);
                int chnk = (ct * 2 + (quad >> 1)) ^ cxs;
                *(ushort4*)&Ps[wv][l16 * 64 + chnk * 8 + (quad & 1) * 4] = pw;
            }

            short8 ap0 = *(const short8*)&Ps[wv][l16 * 64 + ((quad ^ cxs) * 8)];
            short8 ap1 = *(const short8*)&Ps[wv][l16 * 64 + (((4 + quad) ^ cxs) * 8)];
#pragma unroll
            for (int ct = 0; ct < 4; ct++) {
                int vr = (ct * 16 + l16) * 64;
                short8 bv0 = *(const short8*)&VTs[db][g][vr + ((quad ^ cxs) * 8)];
                short8 bv1 = *(const short8*)&VTs[db][g][vr + (((4 + quad) ^ cxs) * 8)];
                o[ct] = __builtin_amdgcn_mfma_f32_16x16x32_bf16(ap0, bv0, o[ct], 0, 0, 0);
                o[ct] = __builtin_amdgcn_mfma_f32_16x16x32_bf16(ap1, bv1, o[ct], 0, 0, 0);
            }
        }
    }

    // combine group partials: group 1 -> LDS, group 0 adds (sums are linear)
    __syncthreads();   // last round's Ks/VTs reads complete before reuse
    float* Of = (float*)&Ks[0][0][0];    // [w4][ct][r][lane] = 16 KB
    float* Lf = (float*)&VTs[0][0][0];   // [w4][lane] = 1 KB
    if (g == 1) {
#pragma unroll
        for (int ct = 0; ct < 4; ct++)
#pragma unroll
            for (int r = 0; r < 4; r++)
                Of[(((w4 * 4 + ct) * 4 + r) * 64) + lane] = o[ct][r];
        Lf[w4 * 64 + lane] = lr;
    }
    __syncthreads();
    if (g == 0) {
#pragma unroll
        for (int ct = 0; ct < 4; ct++)
#pragma unroll
            for (int r = 0; r < 4; r++)
                o[ct][r] += Of[(((w4 * 4 + ct) * 4 + r) * 64) + lane];
        lr += Lf[w4 * 64 + lane];

        // reduce row sums across quads (lane holds q = w4*16 + l16)
        float rs = lr;
        rs += __shfl_xor(rs, 16);
        rs += __shfl_xor(rs, 32);
        int gbase = lane & 48;
        float rinv[4];
#pragma unroll
        for (int r = 0; r < 4; r++)
            rinv[r] = 1.0f / __shfl(rs, gbase + quad * 4 + r);

        int b = bh >> 4, h = bh & 15;
#pragma unroll
        for (int ct = 0; ct < 4; ct++) {
#pragma unroll
            for (int r = 0; r < 4; r++) {
                int q = q0 + w4 * 16 + quad * 4 + r;
                int d = h * 64 + ct * 16 + l16;
                AO[(size_t)(b * TT + q) * DD + d] = f2bf(o[ct][r] * rinv[r]);
            }
        }
    }
}

extern "C" void kernel_launch(void* const* d_in, const int* in_sizes, int n_in,
                              void* d_out, int out_size, void* d_ws, size_t ws_size,
                              hipStream_t stream) {
    const float* x  = (const float*)d_in[0];
    const float* Wq = (const float*)d_in[1];
    const float* Wk = (const float*)d_in[2];
    const float* Wv = (const float*)d_in[3];
    const float* Wo = (const float*)d_in[4];

    u16* xb  = (u16*)d_ws;                       // 8 MB  : x in bf16
    u16* WT  = xb + (size_t)MM * DD;             // 8 MB  : 4 transposed weights bf16
    u16* QKV = WT + (size_t)4 * DD * DD;         // 24 MB : Q,K (b,h,t,dh) + V^T (b,h,dh,t)
    u16* AO  = QKV + (size_t)3 * MM * DD;        // 8 MB  : attention out (B,T,D) bf16
    float* out = (float*)d_out;

    prep_k<<<dim3(32, 32, 5), 256, 0, stream>>>(x, Wq, Wk, Wv, Wo, xb, WT);
    gemm_k3<0, 128, 128><<<dim3(DD / 128, MM / 128, 3), 256, 0, stream>>>(xb, WT, QKV);
    attn_k<<<dim3(32, 32), 512, 0, stream>>>(QKV, AO);
    gemm_k3<1, 64, 128><<<dim3(DD / 128, MM / 64, 1), 256, 0, stream>>>(AO, WT + (size_t)3 * DD * DD, out);
}